// Round 2
// baseline (6341.832 us; speedup 1.0000x reference)
//
#include <hip/hip_runtime.h>
#include <math.h>

#define NN 20000
#define DD 128
#define HH 8
#define PP 8
#define EE 320000
#define LL 4
#define EPSF 1e-4f

// ---------------------------------------------------------------- CSR build
__global__ void count_kernel(const int* __restrict__ dst, int* __restrict__ counts) {
    int e = blockIdx.x * 256 + threadIdx.x;
    if (e < EE) atomicAdd(&counts[dst[e]], 1);
}

__global__ void scan_kernel(const int* __restrict__ counts, int* __restrict__ offs) {
    __shared__ int tmp[1024];
    __shared__ int carry;
    if (threadIdx.x == 0) { carry = 0; offs[0] = 0; }
    __syncthreads();
    for (int base = 0; base < NN; base += 1024) {
        int i = base + threadIdx.x;
        int v = (i < NN) ? counts[i] : 0;
        tmp[threadIdx.x] = v;
        __syncthreads();
        for (int off = 1; off < 1024; off <<= 1) {
            int add = (threadIdx.x >= off) ? tmp[threadIdx.x - off] : 0;
            __syncthreads();
            tmp[threadIdx.x] += add;
            __syncthreads();
        }
        if (i < NN) offs[i + 1] = carry + tmp[threadIdx.x];
        __syncthreads();
        if (threadIdx.x == 0) carry += tmp[1023];
        __syncthreads();
    }
}

__global__ void fill_kernel(const int* __restrict__ dst, const int* __restrict__ offs,
                            int* __restrict__ cursor, int* __restrict__ perm) {
    int e = blockIdx.x * 256 + threadIdx.x;
    if (e < EE) {
        int d = dst[e];
        int p = atomicAdd(&cursor[d], 1);
        perm[offs[d] + p] = e;
    }
}

// ---------------------------------------------------------------- K1: projections (+ save s_old)
// grid ceil(N/8), block 256
__global__ void proj_kernel(const float* __restrict__ x, const float* __restrict__ t,
                            const float* __restrict__ Wq, const float* __restrict__ Wk,
                            const float* __restrict__ Wv,
                            const float* __restrict__ Wpq, const float* __restrict__ Wpk,
                            const float* __restrict__ Wpv,
                            float* __restrict__ s_old,
                            float* __restrict__ q, float* __restrict__ k, float* __restrict__ val,
                            float* __restrict__ pq, float* __restrict__ pk, float* __restrict__ pv) {
    __shared__ float lds[8 * 384];
    int n0 = blockIdx.x * 8;
    int tid = threadIdx.x;
    // phase A: st = [s | t]  (8 nodes x 256)
    for (int idx = tid; idx < 8 * 256; idx += 256) {
        int node = idx >> 8, c = idx & 255;
        int n = n0 + node;
        float vv = 0.f;
        if (n < NN) vv = (c < 128) ? x[(size_t)n * 512 + c] : t[(size_t)n * 128 + (c - 128)];
        lds[node * 256 + c] = vv;
        if (n < NN && c < 128) s_old[(size_t)n * 128 + c] = vv;
    }
    __syncthreads();
    {
        int col = tid & 127;
        int half = tid >> 7;  // nodes half*4 .. +3
        float aq[4] = {0, 0, 0, 0}, ak[4] = {0, 0, 0, 0}, av[4] = {0, 0, 0, 0};
        for (int kk = 0; kk < 256; kk++) {
            float wq = Wq[kk * 128 + col], wk = Wk[kk * 128 + col], wv = Wv[kk * 128 + col];
#pragma unroll
            for (int r = 0; r < 4; r++) {
                float a = lds[(half * 4 + r) * 256 + kk];
                aq[r] += a * wq; ak[r] += a * wk; av[r] += a * wv;
            }
        }
        for (int r = 0; r < 4; r++) {
            int n = n0 + half * 4 + r;
            if (n < NN) {
                q[(size_t)n * 128 + col] = aq[r];
                k[(size_t)n * 128 + col] = ak[r];
                val[(size_t)n * 128 + col] = av[r];
            }
        }
    }
    __syncthreads();
    // phase B: v rows (8 nodes x 3 x 128)
    for (int idx = tid; idx < 8 * 384; idx += 256) {
        int node = idx / 384, c = idx % 384;
        int n = n0 + node;
        lds[node * 384 + c] = (n < NN) ? x[(size_t)n * 512 + 128 + c] : 0.f;
    }
    __syncthreads();
    {
        int hp = tid & 63;
        int grp = tid >> 6;  // nodes grp*2 .. +1
        float apq[3][2], apk[3][2], apv[3][2];
        for (int i = 0; i < 3; i++) for (int r = 0; r < 2; r++) { apq[i][r] = 0; apk[i][r] = 0; apv[i][r] = 0; }
        for (int c = 0; c < 128; c++) {
            float wq = Wpq[c * 64 + hp], wk = Wpk[c * 64 + hp], wv = Wpv[c * 64 + hp];
#pragma unroll
            for (int i = 0; i < 3; i++)
#pragma unroll
                for (int r = 0; r < 2; r++) {
                    float a = lds[(grp * 2 + r) * 384 + i * 128 + c];
                    apq[i][r] += a * wq; apk[i][r] += a * wk; apv[i][r] += a * wv;
                }
        }
        for (int r = 0; r < 2; r++) {
            int n = n0 + grp * 2 + r;
            if (n < NN)
                for (int i = 0; i < 3; i++) {
                    pq[(size_t)n * 192 + i * 64 + hp] = apq[i][r];
                    pk[(size_t)n * 192 + i * 64 + hp] = apk[i][r];
                    pv[(size_t)n * 192 + i * 64 + hp] = apv[i][r];
                }
        }
    }
}

// ---------------------------------------------------------------- K2: edge logits
// grid E/32, block 256 (32 edges x 8 heads)
__global__ void logits_kernel(const int* __restrict__ src, const int* __restrict__ dst,
                              const float* __restrict__ q, const float* __restrict__ k,
                              const float* __restrict__ pq, const float* __restrict__ pk,
                              const float* __restrict__ xe, const float* __restrict__ We_l,
                              const float* __restrict__ gamma_l,
                              float* __restrict__ logits) {
    int tid = threadIdx.x;
    int e = blockIdx.x * 32 + (tid >> 3);
    int h = tid & 7;
    if (e >= EE) return;
    int se = src[e], de = dst[e];
    const float* qd = q + (size_t)de * 128 + h * 16;
    const float* ks = k + (size_t)se * 128 + h * 16;
    float dot = 0.f;
#pragma unroll
    for (int d = 0; d < 16; d++) dot += qd[d] * ks[d];
    float dist = 0.f;
    const float* pqd = pq + (size_t)de * 192 + h * 8;
    const float* pks = pk + (size_t)se * 192 + h * 8;
#pragma unroll
    for (int i = 0; i < 3; i++)
#pragma unroll
        for (int p = 0; p < 8; p++) {
            float dpp = pqd[i * 64 + p] - pks[i * 64 + p];
            dist += dpp * dpp;
        }
    float bias = 0.f;
    const float* xer = xe + (size_t)e * 128;
    for (int c = 0; c < 128; c++) bias += xer[c] * We_l[c * 8 + h];
    float g = gamma_l[h];
    float sp = log1pf(expf(g));
    logits[(size_t)e * 8 + h] = dot * 0.25f + bias - sp * dist;
}

// ---------------------------------------------------------------- K3: per-dst softmax aggregation
// grid N/4, block 256 (one wave per node)
__global__ void agg_kernel(const int* __restrict__ offs, const int* __restrict__ perm,
                           const int* __restrict__ src, const float* __restrict__ logits,
                           const float* __restrict__ val, const float* __restrict__ pv,
                           float* __restrict__ out_s, float* __restrict__ out_p) {
    int wid = threadIdx.x >> 6;
    int lane = threadIdx.x & 63;
    int n = blockIdx.x * 4 + wid;
    if (n >= NN) return;
    int base = offs[n];
    int deg = offs[n + 1] - base;
    // online softmax stats, head = lane (lanes 0..7 meaningful)
    float m = -1e30f, ssum = 0.f;
    if (lane < 8) {
        for (int j = 0; j < deg; j++) {
            int e = perm[base + j];
            float lg = logits[(size_t)e * 8 + lane];
            float mn = fmaxf(m, lg);
            ssum = ssum * __expf(m - mn) + __expf(lg - mn);
            m = mn;
        }
    }
    int hA = lane >> 4;      // head of out_s comp `lane`
    int hB = hA + 4;         // head of out_s comp `lane+64`
    int hC = lane >> 3;      // head of out_p comps
    float mA = __shfl(m, hA), dA = __shfl(ssum, hA);
    float mB = __shfl(m, hB), dB = __shfl(ssum, hB);
    float mC = __shfl(m, hC), dC = __shfl(ssum, hC);
    float rA = (dA > 0.f) ? 1.f / dA : 0.f;
    float rB = (dB > 0.f) ? 1.f / dB : 0.f;
    float rC = (dC > 0.f) ? 1.f / dC : 0.f;
    float accs0 = 0, accs1 = 0, accp0 = 0, accp1 = 0, accp2 = 0;
    for (int j = 0; j < deg; j++) {
        int e = perm[base + j];
        int s_ = src[e];
        float aA = __expf(logits[(size_t)e * 8 + hA] - mA) * rA;
        float aB = __expf(logits[(size_t)e * 8 + hB] - mB) * rB;
        float aC = __expf(logits[(size_t)e * 8 + hC] - mC) * rC;
        accs0 += aA * val[(size_t)s_ * 128 + lane];
        accs1 += aB * val[(size_t)s_ * 128 + 64 + lane];
        accp0 += aC * pv[(size_t)s_ * 192 + lane];
        accp1 += aC * pv[(size_t)s_ * 192 + 64 + lane];
        accp2 += aC * pv[(size_t)s_ * 192 + 128 + lane];
    }
    out_s[(size_t)n * 128 + lane] = accs0;
    out_s[(size_t)n * 128 + 64 + lane] = accs1;
    out_p[(size_t)n * 192 + lane] = accp0;
    out_p[(size_t)n * 192 + 64 + lane] = accp1;
    out_p[(size_t)n * 192 + 128 + lane] = accp2;
}

// ---------------------------------------------------------------- K4: attention output -> x
// grid ceil(N/8), block 256
__global__ void attn_out_kernel(const float* __restrict__ out_s, const float* __restrict__ out_p,
                                const float* __restrict__ Wos_l, const float* __restrict__ Wov_l,
                                float* __restrict__ x) {
    __shared__ float lds[8 * 384];  // per node: out_s[128] | pn[64] | out_p[192]
    int n0 = blockIdx.x * 8;
    int tid = threadIdx.x;
    for (int idx = tid; idx < 8 * 128; idx += 256) {
        int node = idx >> 7, c = idx & 127;
        int n = n0 + node;
        lds[node * 384 + c] = (n < NN) ? out_s[(size_t)n * 128 + c] : 0.f;
    }
    for (int idx = tid; idx < 8 * 192; idx += 256) {
        int node = idx / 192, c = idx % 192;
        int n = n0 + node;
        lds[node * 384 + 192 + c] = (n < NN) ? out_p[(size_t)n * 192 + c] : 0.f;
    }
    __syncthreads();
    for (int idx = tid; idx < 8 * 64; idx += 256) {
        int node = idx >> 6, hp = idx & 63;
        float* b = lds + node * 384;
        float p0 = b[192 + hp], p1 = b[192 + 64 + hp], p2 = b[192 + 128 + hp];
        b[128 + hp] = sqrtf(p0 * p0 + p1 * p1 + p2 * p2 + EPSF);
    }
    __syncthreads();
    int col = tid & 127;
    int grp = tid >> 7;  // nodes grp*4 .. +3
    float as[4] = {0, 0, 0, 0}, av0[4] = {0, 0, 0, 0}, av1[4] = {0, 0, 0, 0}, av2[4] = {0, 0, 0, 0};
    for (int kk = 0; kk < 192; kk++) {
        float w = Wos_l[kk * 128 + col];
#pragma unroll
        for (int r = 0; r < 4; r++) as[r] += lds[(grp * 4 + r) * 384 + kk] * w;
    }
    for (int p = 0; p < 64; p++) {
        float w = Wov_l[p * 128 + col];
#pragma unroll
        for (int r = 0; r < 4; r++) {
            float* b = lds + (grp * 4 + r) * 384 + 192;
            av0[r] += b[p] * w; av1[r] += b[64 + p] * w; av2[r] += b[128 + p] * w;
        }
    }
    for (int r = 0; r < 4; r++) {
        int n = n0 + grp * 4 + r;
        if (n < NN) {
            x[(size_t)n * 512 + col] += as[r];
            x[(size_t)n * 512 + 128 + col] += av0[r];
            x[(size_t)n * 512 + 256 + col] += av1[r];
            x[(size_t)n * 512 + 384 + col] += av2[r];
        }
    }
}

// ---------------------------------------------------------------- K5: fused edge MLP (K=128, half-Hs)
// e_in @ We1 = Y1[src] + Y2[dst] + xe @ We1[256:384]
// LDS ~30 KB -> 5 blocks/CU (vs 46.6 KB / 3 before).
__global__ __launch_bounds__(256) void edge_mlp_kernel(const int* __restrict__ src,
                                                       const int* __restrict__ dst,
                                                       const float* __restrict__ Y1,
                                                       const float* __restrict__ Y2,
                                                       const float* __restrict__ We1c,
                                                       const float* __restrict__ We2_l,
                                                       float* __restrict__ xe) {
    __shared__ float As[16][65];
    __shared__ float Bs[16][132];
    __shared__ float Hs[64][68];   // half of H (64 k-cols at a time)
    int e0 = blockIdx.x * 64;
    int tid = threadIdx.x;
    int ty = tid >> 4, tx = tid & 15;
    float acc[4][8];
    // accumulator init = Y1[src] + Y2[dst]
#pragma unroll
    for (int r = 0; r < 4; r++) {
        int e = e0 + ty * 4 + r;
        const float* y1 = Y1 + (size_t)src[e] * 128;
        const float* y2 = Y2 + (size_t)dst[e] * 128;
        float4 u0 = *(const float4*)(y1 + tx * 4);
        float4 v0 = *(const float4*)(y2 + tx * 4);
        float4 u1 = *(const float4*)(y1 + 64 + tx * 4);
        float4 v1 = *(const float4*)(y2 + 64 + tx * 4);
        acc[r][0] = u0.x + v0.x; acc[r][1] = u0.y + v0.y;
        acc[r][2] = u0.z + v0.z; acc[r][3] = u0.w + v0.w;
        acc[r][4] = u1.x + v1.x; acc[r][5] = u1.y + v1.y;
        acc[r][6] = u1.z + v1.z; acc[r][7] = u1.w + v1.w;
    }
    // GEMM1: acc += xe_tile(64x128) @ We1c(128x128)
    for (int kt = 0; kt < 8; kt++) {
        int kbase = kt * 16;
        {
            int m = tid >> 2, kq = (tid & 3) * 4;
            float4 v = *(const float4*)(xe + (size_t)(e0 + m) * 128 + kbase + kq);
            As[kq + 0][m] = v.x; As[kq + 1][m] = v.y; As[kq + 2][m] = v.z; As[kq + 3][m] = v.w;
        }
#pragma unroll
        for (int i = 0; i < 2; i++) {
            int idx4 = tid * 2 + i;
            int rr = idx4 >> 5, cc = (idx4 & 31) * 4;
            float4 v = *(const float4*)(We1c + (size_t)(kbase + rr) * 128 + cc);
            Bs[rr][cc] = v.x; Bs[rr][cc + 1] = v.y; Bs[rr][cc + 2] = v.z; Bs[rr][cc + 3] = v.w;
        }
        __syncthreads();
#pragma unroll
        for (int kk = 0; kk < 16; kk++) {
            float a[4], b[8];
#pragma unroll
            for (int r = 0; r < 4; r++) a[r] = As[kk][ty * 4 + r];
#pragma unroll
            for (int c = 0; c < 4; c++) { b[c] = Bs[kk][tx * 4 + c]; b[4 + c] = Bs[kk][64 + tx * 4 + c]; }
#pragma unroll
            for (int r = 0; r < 4; r++)
#pragma unroll
                for (int c = 0; c < 8; c++) acc[r][c] += a[r] * b[c];
        }
        __syncthreads();
    }
    // exact GELU in place
#pragma unroll
    for (int r = 0; r < 4; r++)
#pragma unroll
        for (int c = 0; c < 8; c++) {
            float v = acc[r][c];
            acc[r][c] = 0.5f * v * (1.f + erff(v * 0.70710678118f));
        }
    // ---- GEMM2 first half: H[:, 0:64] @ We2[0:64, :]
#pragma unroll
    for (int r = 0; r < 4; r++)
#pragma unroll
        for (int c = 0; c < 4; c++) Hs[ty * 4 + r][tx * 4 + c] = acc[r][c];
    float acc2[4][8];
#pragma unroll
    for (int r = 0; r < 4; r++)
#pragma unroll
        for (int c = 0; c < 8; c++) acc2[r][c] = 0.f;
    for (int kt = 0; kt < 4; kt++) {
        int kbase = kt * 16;
#pragma unroll
        for (int i = 0; i < 2; i++) {
            int idx4 = tid * 2 + i;
            int rr = idx4 >> 5, cc = (idx4 & 31) * 4;
            float4 v = *(const float4*)(We2_l + (size_t)(kbase + rr) * 128 + cc);
            Bs[rr][cc] = v.x; Bs[rr][cc + 1] = v.y; Bs[rr][cc + 2] = v.z; Bs[rr][cc + 3] = v.w;
        }
        __syncthreads();
#pragma unroll
        for (int kk = 0; kk < 16; kk++) {
            float a[4], b[8];
#pragma unroll
            for (int r = 0; r < 4; r++) a[r] = Hs[ty * 4 + r][kbase + kk];
#pragma unroll
            for (int c = 0; c < 4; c++) { b[c] = Bs[kk][tx * 4 + c]; b[4 + c] = Bs[kk][64 + tx * 4 + c]; }
#pragma unroll
            for (int r = 0; r < 4; r++)
#pragma unroll
                for (int c = 0; c < 8; c++) acc2[r][c] += a[r] * b[c];
        }
        __syncthreads();
    }
    // ---- GEMM2 second half: H[:, 64:128] @ We2[64:128, :]
#pragma unroll
    for (int r = 0; r < 4; r++)
#pragma unroll
        for (int c = 0; c < 4; c++) Hs[ty * 4 + r][tx * 4 + c] = acc[r][4 + c];
    for (int kt = 4; kt < 8; kt++) {
        int kbase = kt * 16;
#pragma unroll
        for (int i = 0; i < 2; i++) {
            int idx4 = tid * 2 + i;
            int rr = idx4 >> 5, cc = (idx4 & 31) * 4;
            float4 v = *(const float4*)(We2_l + (size_t)(kbase + rr) * 128 + cc);
            Bs[rr][cc] = v.x; Bs[rr][cc + 1] = v.y; Bs[rr][cc + 2] = v.z; Bs[rr][cc + 3] = v.w;
        }
        __syncthreads();
#pragma unroll
        for (int kk = 0; kk < 16; kk++) {
            float a[4], b[8];
#pragma unroll
            for (int r = 0; r < 4; r++) a[r] = Hs[ty * 4 + r][(kbase - 64) + kk];
#pragma unroll
            for (int c = 0; c < 4; c++) { b[c] = Bs[kk][tx * 4 + c]; b[4 + c] = Bs[kk][64 + tx * 4 + c]; }
#pragma unroll
            for (int r = 0; r < 4; r++)
#pragma unroll
                for (int c = 0; c < 8; c++) acc2[r][c] += a[r] * b[c];
        }
        __syncthreads();
    }
#pragma unroll
    for (int r = 0; r < 4; r++) {
        float* row = xe + (size_t)(e0 + ty * 4 + r) * 128;
        float4 o0 = *(const float4*)(row + tx * 4);
        float4 o1 = *(const float4*)(row + 64 + tx * 4);
        o0.x += acc2[r][0]; o0.y += acc2[r][1]; o0.z += acc2[r][2]; o0.w += acc2[r][3];
        o1.x += acc2[r][4]; o1.y += acc2[r][5]; o1.z += acc2[r][6]; o1.w += acc2[r][7];
        *(float4*)(row + tx * 4) = o0;
        *(float4*)(row + 64 + tx * 4) = o1;
    }
}

// ---------------------------------------------------------------- K6: build z
__global__ void zprep_kernel(const float* __restrict__ x, const float* __restrict__ R,
                             float* __restrict__ z) {
    int idx = blockIdx.x * 256 + threadIdx.x;
    if (idx >= NN * 128) return;
    int n = idx >> 7, c = idx & 127;
    float v0 = x[(size_t)n * 512 + 128 + c];
    float v1 = x[(size_t)n * 512 + 256 + c];
    float v2 = x[(size_t)n * 512 + 384 + c];
    const float* Rn = R + (size_t)n * 9;
    float* zr = z + (size_t)n * 640;
    zr[c] = x[(size_t)n * 512 + c];
    zr[128 + c * 3 + 0] = v0 * Rn[0] + v1 * Rn[3] + v2 * Rn[6];
    zr[128 + c * 3 + 1] = v0 * Rn[1] + v1 * Rn[4] + v2 * Rn[7];
    zr[128 + c * 3 + 2] = v0 * Rn[2] + v1 * Rn[5] + v2 * Rn[8];
    zr[512 + c] = sqrtf(v0 * v0 + v1 * v1 + v2 * v2 + EPSF);
}

// ---------------------------------------------------------------- K7/K8: 128x128-tile GEMM + bias (+gelu)
// grid (ceil(M/128), Nc/128), block 256 (16x16 thread grid, 8x8 micro-tile).
// Per kk: 64 FMA / 4 ds_read_b128 (2x the density of the 64-tile version).
// A staged transposed As[k][m]; B reads split-column (tx*4, 64+tx*4) -> conflict-free.
template <int ACT>
__global__ __launch_bounds__(256) void gemm128_kernel(const float* __restrict__ A,
                                                      const float* __restrict__ B,
                                                      const float* __restrict__ bias,
                                                      float* __restrict__ C,
                                                      int M, int K, int Nc) {
    __shared__ float As[16][132];
    __shared__ float Bs[16][132];
    int m0 = blockIdx.x * 128;
    int n0_ = blockIdx.y * 128;
    int tid = threadIdx.x;
    int ty = tid >> 4, tx = tid & 15;
    float acc[8][8];
#pragma unroll
    for (int r = 0; r < 8; r++)
#pragma unroll
        for (int c = 0; c < 8; c++) acc[r][c] = 0.f;
    for (int kt = 0; kt < K; kt += 16) {
        // A stage: 128 rows x 16 k, transposed. thread: row m=tid>>1, k-span kq..kq+7
        {
            int m = tid >> 1, kq = (tid & 1) * 8;
            int gm = m0 + m;
            float4 v0 = make_float4(0.f, 0.f, 0.f, 0.f), v1 = v0;
            if (gm < M) {
                const float* ap = A + (size_t)gm * K + kt + kq;
                v0 = *(const float4*)(ap);
                v1 = *(const float4*)(ap + 4);
            }
            As[kq + 0][m] = v0.x; As[kq + 1][m] = v0.y; As[kq + 2][m] = v0.z; As[kq + 3][m] = v0.w;
            As[kq + 4][m] = v1.x; As[kq + 5][m] = v1.y; As[kq + 6][m] = v1.z; As[kq + 7][m] = v1.w;
        }
        // B stage: 16 rows x 128 cols; consecutive lanes -> consecutive float4 (conflict-free)
#pragma unroll
        for (int i = 0; i < 2; i++) {
            int f = i * 256 + tid;
            int rr = f >> 5, c4 = (f & 31) * 4;
            float4 v = *(const float4*)(B + (size_t)(kt + rr) * Nc + n0_ + c4);
            *(float4*)&Bs[rr][c4] = v;
        }
        __syncthreads();
#pragma unroll
        for (int kk = 0; kk < 16; kk++) {
            float a[8], b[8];
            *(float4*)(a + 0) = *(const float4*)&As[kk][ty * 8];
            *(float4*)(a + 4) = *(const float4*)&As[kk][ty * 8 + 4];
            *(float4*)(b + 0) = *(const float4*)&Bs[kk][tx * 4];
            *(float4*)(b + 4) = *(const float4*)&Bs[kk][64 + tx * 4];
#pragma unroll
            for (int r = 0; r < 8; r++)
#pragma unroll
                for (int c = 0; c < 8; c++) acc[r][c] += a[r] * b[c];
        }
        __syncthreads();
    }
    // epilogue
    float4 b0 = make_float4(0.f, 0.f, 0.f, 0.f), b1 = b0;
    if (bias) {
        b0 = *(const float4*)(bias + n0_ + tx * 4);
        b1 = *(const float4*)(bias + n0_ + 64 + tx * 4);
    }
#pragma unroll
    for (int r = 0; r < 8; r++) {
        int gm = m0 + ty * 8 + r;
        if (gm < M) {
            float4 o0, o1;
            o0.x = acc[r][0] + b0.x; o0.y = acc[r][1] + b0.y;
            o0.z = acc[r][2] + b0.z; o0.w = acc[r][3] + b0.w;
            o1.x = acc[r][4] + b1.x; o1.y = acc[r][5] + b1.y;
            o1.z = acc[r][6] + b1.z; o1.w = acc[r][7] + b1.w;
            if (ACT) {
                o0.x = 0.5f * o0.x * (1.f + erff(o0.x * 0.70710678118f));
                o0.y = 0.5f * o0.y * (1.f + erff(o0.y * 0.70710678118f));
                o0.z = 0.5f * o0.z * (1.f + erff(o0.z * 0.70710678118f));
                o0.w = 0.5f * o0.w * (1.f + erff(o0.w * 0.70710678118f));
                o1.x = 0.5f * o1.x * (1.f + erff(o1.x * 0.70710678118f));
                o1.y = 0.5f * o1.y * (1.f + erff(o1.y * 0.70710678118f));
                o1.z = 0.5f * o1.z * (1.f + erff(o1.z * 0.70710678118f));
                o1.w = 0.5f * o1.w * (1.f + erff(o1.w * 0.70710678118f));
            }
            *(float4*)(C + (size_t)gm * Nc + n0_ + tx * 4) = o0;
            *(float4*)(C + (size_t)gm * Nc + n0_ + 64 + tx * 4) = o1;
        }
    }
}

// ---------------------------------------------------------------- K9: finalize local update
__global__ void final_kernel(const float* __restrict__ h, const float* __restrict__ R,
                             float* __restrict__ x) {
    int idx = blockIdx.x * 256 + threadIdx.x;
    if (idx >= NN * 128) return;
    int n = idx >> 7, c = idx & 127;
    const float* hr = h + (size_t)n * 512;
    const float* Rn = R + (size_t)n * 9;
    float h1 = hr[128 + c], h2 = hr[256 + c], h3 = hr[384 + c];
    x[(size_t)n * 512 + c] += hr[c];
    x[(size_t)n * 512 + 128 + c] += Rn[0] * h1 + Rn[1] * h2 + Rn[2] * h3;
    x[(size_t)n * 512 + 256 + c] += Rn[3] * h1 + Rn[4] * h2 + Rn[5] * h3;
    x[(size_t)n * 512 + 384 + c] += Rn[6] * h1 + Rn[7] * h2 + Rn[8] * h3;
}

// ================================================================ launcher
extern "C" void kernel_launch(void* const* d_in, const int* in_sizes, int n_in,
                              void* d_out, int out_size, void* d_ws, size_t ws_size,
                              hipStream_t stream) {
    const float* x_in = (const float*)d_in[0];
    const float* t    = (const float*)d_in[1];
    const float* R    = (const float*)d_in[2];
    const float* xe_in = (const float*)d_in[3];
    const int* ei     = (const int*)d_in[4];
    const float* Wq   = (const float*)d_in[5];
    const float* Wk   = (const float*)d_in[6];
    const float* Wv   = (const float*)d_in[7];
    const float* Wpq  = (const float*)d_in[8];
    const float* Wpk  = (const float*)d_in[9];
    const float* Wpv  = (const float*)d_in[10];
    const float* We   = (const float*)d_in[11];
    const float* gamma = (const float*)d_in[12];
    const float* Wos  = (const float*)d_in[13];
    const float* Wov  = (const float*)d_in[14];
    const float* We1  = (const float*)d_in[15];
    const float* We2  = (const float*)d_in[16];
    const float* luW1 = (const float*)d_in[17];
    const float* lub1 = (const float*)d_in[18];
    const float* luW2 = (const float*)d_in[19];
    const float* lub2 = (const float*)d_in[20];

    float* x  = (float*)d_out;                      // (N,4,128)
    float* xe = (float*)d_out + (size_t)NN * 512;   // (E,128)

    // workspace carve (floats)
    float* fws = (float*)d_ws;
    float* s_old = fws;                     fws += (size_t)NN * 128;
    float* U = fws;                         fws += (size_t)NN * 1792;
    float* logits = fws;                    fws += (size_t)EE * 8;
    int* iws = (int*)fws;
    int* counts = iws;                      iws += NN + 1;
    int* offs = iws;                        iws += NN + 1;
    int* cursor = iws;                      iws += NN + 1;
    int* perm = iws;                        iws += EE;

    // aliased by lifetime inside U
    float* q  = U;
    float* k  = U + (size_t)NN * 128;
    float* vv = U + (size_t)NN * 256;
    float* pq = U + (size_t)NN * 384;
    float* pk = U + (size_t)NN * 576;
    float* pv = U + (size_t)NN * 768;
    float* out_s = U + (size_t)NN * 960;
    float* out_p = U + (size_t)NN * 1088;
    float* Y1 = U + (size_t)NN * 1280;      // node-side We1 projections (dead before h written)
    float* Y2 = U + (size_t)NN * 1408;
    float* z  = U;                          // after attention phase
    float* h1 = U + (size_t)NN * 640;
    float* h  = U + (size_t)NN * 1280;

    const int* srcp = ei;
    const int* dstp = ei + EE;

    hipMemcpyAsync(x, x_in, (size_t)NN * 512 * 4, hipMemcpyDeviceToDevice, stream);
    hipMemcpyAsync(xe, xe_in, (size_t)EE * 128 * 4, hipMemcpyDeviceToDevice, stream);
    hipMemsetAsync(counts, 0, (NN + 1) * 4, stream);
    hipMemsetAsync(cursor, 0, (NN + 1) * 4, stream);
    count_kernel<<<(EE + 255) / 256, 256, 0, stream>>>(dstp, counts);
    scan_kernel<<<1, 1024, 0, stream>>>(counts, offs);
    fill_kernel<<<(EE + 255) / 256, 256, 0, stream>>>(dstp, offs, cursor, perm);

    const int GN = (NN + 127) / 128;  // 157

    for (int l = 0; l < LL; l++) {
        const float* Wq_l = Wq + (size_t)l * 256 * 128;
        const float* Wk_l = Wk + (size_t)l * 256 * 128;
        const float* Wv_l = Wv + (size_t)l * 256 * 128;
        const float* Wpq_l = Wpq + (size_t)l * 128 * 64;
        const float* Wpk_l = Wpk + (size_t)l * 128 * 64;
        const float* Wpv_l = Wpv + (size_t)l * 128 * 64;
        const float* We_l = We + (size_t)l * 128 * 8;
        const float* gamma_l = gamma + (size_t)l * 8;
        const float* Wos_l = Wos + (size_t)l * 192 * 128;
        const float* Wov_l = Wov + (size_t)l * 64 * 128;
        const float* We1_l = We1 + (size_t)l * 384 * 128;
        const float* We2_l = We2 + (size_t)l * 128 * 128;
        const float* luW1_l = luW1 + (size_t)l * 640 * 640;
        const float* lub1_l = lub1 + (size_t)l * 640;
        const float* luW2_l = luW2 + (size_t)l * 640 * 512;
        const float* lub2_l = lub2 + (size_t)l * 512;

        proj_kernel<<<(NN + 7) / 8, 256, 0, stream>>>(x, t, Wq_l, Wk_l, Wv_l, Wpq_l, Wpk_l,
                                                      Wpv_l, s_old, q, k, vv, pq, pk, pv);
        // node-side pieces of the edge-MLP first GEMM:
        // Y1 = s_old @ We1[0:128], Y2 = s_old @ We1[128:256]
        gemm128_kernel<0><<<dim3(GN, 1), 256, 0, stream>>>(s_old, We1_l, nullptr, Y1,
                                                           NN, 128, 128);
        gemm128_kernel<0><<<dim3(GN, 1), 256, 0, stream>>>(s_old, We1_l + 128 * 128, nullptr, Y2,
                                                           NN, 128, 128);
        logits_kernel<<<EE / 32, 256, 0, stream>>>(srcp, dstp, q, k, pq, pk, xe, We_l, gamma_l,
                                                   logits);
        agg_kernel<<<NN / 4, 256, 0, stream>>>(offs, perm, srcp, logits, vv, pv, out_s, out_p);
        attn_out_kernel<<<(NN + 7) / 8, 256, 0, stream>>>(out_s, out_p, Wos_l, Wov_l, x);
        edge_mlp_kernel<<<EE / 64, 256, 0, stream>>>(srcp, dstp, Y1, Y2, We1_l + 256 * 128,
                                                     We2_l, xe);
        zprep_kernel<<<(NN * 128 + 255) / 256, 256, 0, stream>>>(x, R, z);
        gemm128_kernel<1><<<dim3(GN, 5), 256, 0, stream>>>(z, luW1_l, lub1_l, h1,
                                                           NN, 640, 640);
        gemm128_kernel<0><<<dim3(GN, 4), 256, 0, stream>>>(h1, luW2_l, lub2_l, h,
                                                           NN, 640, 512);
        final_kernel<<<(NN * 128 + 255) / 256, 256, 0, stream>>>(h, R, x);
    }
}

// Round 3
// 5763.232 us; speedup vs baseline: 1.1004x; 1.1004x over previous
//
#include <hip/hip_runtime.h>
#include <math.h>

#define NN 20000
#define DD 128
#define HH 8
#define PP 8
#define EE 320000
#define LL 4
#define EPSF 1e-4f

// ---------------------------------------------------------------- CSR build
__global__ void count_kernel(const int* __restrict__ dst, int* __restrict__ counts) {
    int e = blockIdx.x * 256 + threadIdx.x;
    if (e < EE) atomicAdd(&counts[dst[e]], 1);
}

__global__ void scan_kernel(const int* __restrict__ counts, int* __restrict__ offs) {
    __shared__ int tmp[1024];
    __shared__ int carry;
    if (threadIdx.x == 0) { carry = 0; offs[0] = 0; }
    __syncthreads();
    for (int base = 0; base < NN; base += 1024) {
        int i = base + threadIdx.x;
        int v = (i < NN) ? counts[i] : 0;
        tmp[threadIdx.x] = v;
        __syncthreads();
        for (int off = 1; off < 1024; off <<= 1) {
            int add = (threadIdx.x >= off) ? tmp[threadIdx.x - off] : 0;
            __syncthreads();
            tmp[threadIdx.x] += add;
            __syncthreads();
        }
        if (i < NN) offs[i + 1] = carry + tmp[threadIdx.x];
        __syncthreads();
        if (threadIdx.x == 0) carry += tmp[1023];
        __syncthreads();
    }
}

__global__ void fill_kernel(const int* __restrict__ dst, const int* __restrict__ offs,
                            int* __restrict__ cursor, int* __restrict__ perm) {
    int e = blockIdx.x * 256 + threadIdx.x;
    if (e < EE) {
        int d = dst[e];
        int p = atomicAdd(&cursor[d], 1);
        perm[offs[d] + p] = e;
    }
}

// ---------------------------------------------------------------- K1: projections (+ save s_old)
// grid ceil(N/8), block 256
__global__ void proj_kernel(const float* __restrict__ x, const float* __restrict__ t,
                            const float* __restrict__ Wq, const float* __restrict__ Wk,
                            const float* __restrict__ Wv,
                            const float* __restrict__ Wpq, const float* __restrict__ Wpk,
                            const float* __restrict__ Wpv,
                            float* __restrict__ s_old,
                            float* __restrict__ q, float* __restrict__ k, float* __restrict__ val,
                            float* __restrict__ pq, float* __restrict__ pk, float* __restrict__ pv) {
    __shared__ float lds[8 * 384];
    int n0 = blockIdx.x * 8;
    int tid = threadIdx.x;
    // phase A: st = [s | t]  (8 nodes x 256)
    for (int idx = tid; idx < 8 * 256; idx += 256) {
        int node = idx >> 8, c = idx & 255;
        int n = n0 + node;
        float vv = 0.f;
        if (n < NN) vv = (c < 128) ? x[(size_t)n * 512 + c] : t[(size_t)n * 128 + (c - 128)];
        lds[node * 256 + c] = vv;
        if (n < NN && c < 128) s_old[(size_t)n * 128 + c] = vv;
    }
    __syncthreads();
    {
        int col = tid & 127;
        int half = tid >> 7;  // nodes half*4 .. +3
        float aq[4] = {0, 0, 0, 0}, ak[4] = {0, 0, 0, 0}, av[4] = {0, 0, 0, 0};
        for (int kk = 0; kk < 256; kk++) {
            float wq = Wq[kk * 128 + col], wk = Wk[kk * 128 + col], wv = Wv[kk * 128 + col];
#pragma unroll
            for (int r = 0; r < 4; r++) {
                float a = lds[(half * 4 + r) * 256 + kk];
                aq[r] += a * wq; ak[r] += a * wk; av[r] += a * wv;
            }
        }
        for (int r = 0; r < 4; r++) {
            int n = n0 + half * 4 + r;
            if (n < NN) {
                q[(size_t)n * 128 + col] = aq[r];
                k[(size_t)n * 128 + col] = ak[r];
                val[(size_t)n * 128 + col] = av[r];
            }
        }
    }
    __syncthreads();
    // phase B: v rows (8 nodes x 3 x 128)
    for (int idx = tid; idx < 8 * 384; idx += 256) {
        int node = idx / 384, c = idx % 384;
        int n = n0 + node;
        lds[node * 384 + c] = (n < NN) ? x[(size_t)n * 512 + 128 + c] : 0.f;
    }
    __syncthreads();
    {
        int hp = tid & 63;
        int grp = tid >> 6;  // nodes grp*2 .. +1
        float apq[3][2], apk[3][2], apv[3][2];
        for (int i = 0; i < 3; i++) for (int r = 0; r < 2; r++) { apq[i][r] = 0; apk[i][r] = 0; apv[i][r] = 0; }
        for (int c = 0; c < 128; c++) {
            float wq = Wpq[c * 64 + hp], wk = Wpk[c * 64 + hp], wv = Wpv[c * 64 + hp];
#pragma unroll
            for (int i = 0; i < 3; i++)
#pragma unroll
                for (int r = 0; r < 2; r++) {
                    float a = lds[(grp * 2 + r) * 384 + i * 128 + c];
                    apq[i][r] += a * wq; apk[i][r] += a * wk; apv[i][r] += a * wv;
                }
        }
        for (int r = 0; r < 2; r++) {
            int n = n0 + grp * 2 + r;
            if (n < NN)
                for (int i = 0; i < 3; i++) {
                    pq[(size_t)n * 192 + i * 64 + hp] = apq[i][r];
                    pk[(size_t)n * 192 + i * 64 + hp] = apk[i][r];
                    pv[(size_t)n * 192 + i * 64 + hp] = apv[i][r];
                }
        }
    }
}

// ---------------------------------------------------------------- K2: edge logits
// grid E/32, block 256 (32 edges x 8 heads)
__global__ void logits_kernel(const int* __restrict__ src, const int* __restrict__ dst,
                              const float* __restrict__ q, const float* __restrict__ k,
                              const float* __restrict__ pq, const float* __restrict__ pk,
                              const float* __restrict__ xe, const float* __restrict__ We_l,
                              const float* __restrict__ gamma_l,
                              float* __restrict__ logits) {
    int tid = threadIdx.x;
    int e = blockIdx.x * 32 + (tid >> 3);
    int h = tid & 7;
    if (e >= EE) return;
    int se = src[e], de = dst[e];
    const float* qd = q + (size_t)de * 128 + h * 16;
    const float* ks = k + (size_t)se * 128 + h * 16;
    float dot = 0.f;
#pragma unroll
    for (int d = 0; d < 16; d++) dot += qd[d] * ks[d];
    float dist = 0.f;
    const float* pqd = pq + (size_t)de * 192 + h * 8;
    const float* pks = pk + (size_t)se * 192 + h * 8;
#pragma unroll
    for (int i = 0; i < 3; i++)
#pragma unroll
        for (int p = 0; p < 8; p++) {
            float dpp = pqd[i * 64 + p] - pks[i * 64 + p];
            dist += dpp * dpp;
        }
    float bias = 0.f;
    const float* xer = xe + (size_t)e * 128;
    for (int c = 0; c < 128; c++) bias += xer[c] * We_l[c * 8 + h];
    float g = gamma_l[h];
    float sp = log1pf(expf(g));
    logits[(size_t)e * 8 + h] = dot * 0.25f + bias - sp * dist;
}

// ---------------------------------------------------------------- K3: per-dst softmax aggregation
// grid N/4, block 256 (one wave per node)
// pass-1: all 64 lanes (8 j-slices x 8 heads) + shuffle online-softmax combine.
// pass-2: perm/src prefetched one iteration ahead (cuts the 3-deep gather chain).
__global__ void agg_kernel(const int* __restrict__ offs, const int* __restrict__ perm,
                           const int* __restrict__ src, const float* __restrict__ logits,
                           const float* __restrict__ val, const float* __restrict__ pv,
                           float* __restrict__ out_s, float* __restrict__ out_p) {
    int wid = threadIdx.x >> 6;
    int lane = threadIdx.x & 63;
    int n = blockIdx.x * 4 + wid;
    if (n >= NN) return;
    int base = offs[n];
    int deg = offs[n + 1] - base;
    // online softmax stats: lane = js*8 + h
    float m = -1e30f, ssum = 0.f;
    {
        int h = lane & 7, js = lane >> 3;
        for (int j = js; j < deg; j += 8) {
            int e = perm[base + j];
            float lg = logits[(size_t)e * 8 + h];
            float mn = fmaxf(m, lg);
            ssum = ssum * __expf(m - mn) + __expf(lg - mn);
            m = mn;
        }
        // combine across the 8 j-slices (lanes differing in bits 3..5)
#pragma unroll
        for (int off = 8; off < 64; off <<= 1) {
            float mo = __shfl_xor(m, off);
            float so = __shfl_xor(ssum, off);
            float mn = fmaxf(m, mo);
            ssum = ssum * __expf(m - mn) + so * __expf(mo - mn);
            m = mn;
        }
    }
    int hA = lane >> 4;      // head of out_s comp `lane`
    int hB = hA + 4;         // head of out_s comp `lane+64`
    int hC = lane >> 3;      // head of out_p comps
    float mA = __shfl(m, hA), dA = __shfl(ssum, hA);
    float mB = __shfl(m, hB), dB = __shfl(ssum, hB);
    float mC = __shfl(m, hC), dC = __shfl(ssum, hC);
    float rA = (dA > 0.f) ? 1.f / dA : 0.f;
    float rB = (dB > 0.f) ? 1.f / dB : 0.f;
    float rC = (dC > 0.f) ? 1.f / dC : 0.f;
    float accs0 = 0, accs1 = 0, accp0 = 0, accp1 = 0, accp2 = 0;
    int ecur = 0, scur = 0;
    if (deg > 0) { ecur = perm[base]; scur = src[ecur]; }
    for (int j = 0; j < deg; j++) {
        int e = ecur, s_ = scur;
        if (j + 1 < deg) { ecur = perm[base + j + 1]; scur = src[ecur]; }
        float aA = __expf(logits[(size_t)e * 8 + hA] - mA) * rA;
        float aB = __expf(logits[(size_t)e * 8 + hB] - mB) * rB;
        float aC = __expf(logits[(size_t)e * 8 + hC] - mC) * rC;
        accs0 += aA * val[(size_t)s_ * 128 + lane];
        accs1 += aB * val[(size_t)s_ * 128 + 64 + lane];
        accp0 += aC * pv[(size_t)s_ * 192 + lane];
        accp1 += aC * pv[(size_t)s_ * 192 + 64 + lane];
        accp2 += aC * pv[(size_t)s_ * 192 + 128 + lane];
    }
    out_s[(size_t)n * 128 + lane] = accs0;
    out_s[(size_t)n * 128 + 64 + lane] = accs1;
    out_p[(size_t)n * 192 + lane] = accp0;
    out_p[(size_t)n * 192 + 64 + lane] = accp1;
    out_p[(size_t)n * 192 + 128 + lane] = accp2;
}

// ---------------------------------------------------------------- K4: attention output -> x
// grid ceil(N/8), block 256
__global__ void attn_out_kernel(const float* __restrict__ out_s, const float* __restrict__ out_p,
                                const float* __restrict__ Wos_l, const float* __restrict__ Wov_l,
                                float* __restrict__ x) {
    __shared__ float lds[8 * 384];  // per node: out_s[128] | pn[64] | out_p[192]
    int n0 = blockIdx.x * 8;
    int tid = threadIdx.x;
    for (int idx = tid; idx < 8 * 128; idx += 256) {
        int node = idx >> 7, c = idx & 127;
        int n = n0 + node;
        lds[node * 384 + c] = (n < NN) ? out_s[(size_t)n * 128 + c] : 0.f;
    }
    for (int idx = tid; idx < 8 * 192; idx += 256) {
        int node = idx / 192, c = idx % 192;
        int n = n0 + node;
        lds[node * 384 + 192 + c] = (n < NN) ? out_p[(size_t)n * 192 + c] : 0.f;
    }
    __syncthreads();
    for (int idx = tid; idx < 8 * 64; idx += 256) {
        int node = idx >> 6, hp = idx & 63;
        float* b = lds + node * 384;
        float p0 = b[192 + hp], p1 = b[192 + 64 + hp], p2 = b[192 + 128 + hp];
        b[128 + hp] = sqrtf(p0 * p0 + p1 * p1 + p2 * p2 + EPSF);
    }
    __syncthreads();
    int col = tid & 127;
    int grp = tid >> 7;  // nodes grp*4 .. +3
    float as[4] = {0, 0, 0, 0}, av0[4] = {0, 0, 0, 0}, av1[4] = {0, 0, 0, 0}, av2[4] = {0, 0, 0, 0};
    for (int kk = 0; kk < 192; kk++) {
        float w = Wos_l[kk * 128 + col];
#pragma unroll
        for (int r = 0; r < 4; r++) as[r] += lds[(grp * 4 + r) * 384 + kk] * w;
    }
    for (int p = 0; p < 64; p++) {
        float w = Wov_l[p * 128 + col];
#pragma unroll
        for (int r = 0; r < 4; r++) {
            float* b = lds + (grp * 4 + r) * 384 + 192;
            av0[r] += b[p] * w; av1[r] += b[64 + p] * w; av2[r] += b[128 + p] * w;
        }
    }
    for (int r = 0; r < 4; r++) {
        int n = n0 + grp * 4 + r;
        if (n < NN) {
            x[(size_t)n * 512 + col] += as[r];
            x[(size_t)n * 512 + 128 + col] += av0[r];
            x[(size_t)n * 512 + 256 + col] += av1[r];
            x[(size_t)n * 512 + 384 + col] += av2[r];
        }
    }
}

// ---------------------------------------------------------------- K5: fused edge MLP (K=128)
// e_in @ We1 = Y1[src] + Y2[dst] + xe @ We1[256:384]
// R1 structure + register-prefetch double-buffering (stage latency hidden under
// compute) + Hs padded to 133 (stride 132 was an 8-way bank conflict on row reads).
__global__ __launch_bounds__(256) void edge_mlp_kernel(const int* __restrict__ src,
                                                       const int* __restrict__ dst,
                                                       const float* __restrict__ Y1,
                                                       const float* __restrict__ Y2,
                                                       const float* __restrict__ We1c,
                                                       const float* __restrict__ We2_l,
                                                       float* __restrict__ xe) {
    __shared__ float As[16][65];
    __shared__ float Bs[16][132];
    __shared__ float Hs[64][133];
    int e0 = blockIdx.x * 64;
    int tid = threadIdx.x;
    int ty = tid >> 4, tx = tid & 15;
    int am = tid >> 2, akq = (tid & 3) * 4;
    int brr = (tid * 2) >> 5, bcc = ((tid * 2) & 31) * 4;
    float acc[4][8];
    // accumulator init = Y1[src] + Y2[dst]
#pragma unroll
    for (int r = 0; r < 4; r++) {
        int e = e0 + ty * 4 + r;
        const float* y1 = Y1 + (size_t)src[e] * 128;
        const float* y2 = Y2 + (size_t)dst[e] * 128;
        float4 u0 = *(const float4*)(y1 + tx * 4);
        float4 v0 = *(const float4*)(y2 + tx * 4);
        float4 u1 = *(const float4*)(y1 + 64 + tx * 4);
        float4 v1 = *(const float4*)(y2 + 64 + tx * 4);
        acc[r][0] = u0.x + v0.x; acc[r][1] = u0.y + v0.y;
        acc[r][2] = u0.z + v0.z; acc[r][3] = u0.w + v0.w;
        acc[r][4] = u1.x + v1.x; acc[r][5] = u1.y + v1.y;
        acc[r][6] = u1.z + v1.z; acc[r][7] = u1.w + v1.w;
    }
    // GEMM1: acc += xe_tile(64x128) @ We1c(128x128), prefetched double-buffer
    float4 pa, pb0, pb1;
    pa  = *(const float4*)(xe + (size_t)(e0 + am) * 128 + akq);
    pb0 = *(const float4*)(We1c + (size_t)brr * 128 + bcc);
    pb1 = *(const float4*)(We1c + (size_t)brr * 128 + bcc + 4);
    for (int kt = 0; kt < 8; kt++) {
        As[akq + 0][am] = pa.x; As[akq + 1][am] = pa.y;
        As[akq + 2][am] = pa.z; As[akq + 3][am] = pa.w;
        *(float4*)&Bs[brr][bcc] = pb0;
        *(float4*)&Bs[brr][bcc + 4] = pb1;
        __syncthreads();
        if (kt < 7) {
            int kb = (kt + 1) * 16;
            pa  = *(const float4*)(xe + (size_t)(e0 + am) * 128 + kb + akq);
            pb0 = *(const float4*)(We1c + (size_t)(kb + brr) * 128 + bcc);
            pb1 = *(const float4*)(We1c + (size_t)(kb + brr) * 128 + bcc + 4);
        } else {
            // prefetch GEMM2 phase-0 B
            pb0 = *(const float4*)(We2_l + (size_t)brr * 128 + bcc);
            pb1 = *(const float4*)(We2_l + (size_t)brr * 128 + bcc + 4);
        }
#pragma unroll
        for (int kk = 0; kk < 16; kk++) {
            float a[4], b[8];
#pragma unroll
            for (int r = 0; r < 4; r++) a[r] = As[kk][ty * 4 + r];
            *(float4*)(b + 0) = *(const float4*)&Bs[kk][tx * 4];
            *(float4*)(b + 4) = *(const float4*)&Bs[kk][64 + tx * 4];
#pragma unroll
            for (int r = 0; r < 4; r++)
#pragma unroll
                for (int c = 0; c < 8; c++) acc[r][c] += a[r] * b[c];
        }
        __syncthreads();
    }
    // exact GELU -> Hs
#pragma unroll
    for (int r = 0; r < 4; r++)
#pragma unroll
        for (int c = 0; c < 4; c++) {
            float v = acc[r][c];
            Hs[ty * 4 + r][tx * 4 + c] = 0.5f * v * (1.f + erff(v * 0.70710678118f));
            float w = acc[r][4 + c];
            Hs[ty * 4 + r][64 + tx * 4 + c] = 0.5f * w * (1.f + erff(w * 0.70710678118f));
        }
    // reuse acc as acc2
#pragma unroll
    for (int r = 0; r < 4; r++)
#pragma unroll
        for (int c = 0; c < 8; c++) acc[r][c] = 0.f;
    __syncthreads();
    // GEMM2: Hs(64x128) @ We2(128x128), B prefetched
    for (int kt = 0; kt < 8; kt++) {
        int kbase = kt * 16;
        *(float4*)&Bs[brr][bcc] = pb0;
        *(float4*)&Bs[brr][bcc + 4] = pb1;
        __syncthreads();
        if (kt < 7) {
            int kb = (kt + 1) * 16;
            pb0 = *(const float4*)(We2_l + (size_t)(kb + brr) * 128 + bcc);
            pb1 = *(const float4*)(We2_l + (size_t)(kb + brr) * 128 + bcc + 4);
        }
#pragma unroll
        for (int kk = 0; kk < 16; kk++) {
            float a[4], b[8];
#pragma unroll
            for (int r = 0; r < 4; r++) a[r] = Hs[ty * 4 + r][kbase + kk];
            *(float4*)(b + 0) = *(const float4*)&Bs[kk][tx * 4];
            *(float4*)(b + 4) = *(const float4*)&Bs[kk][64 + tx * 4];
#pragma unroll
            for (int r = 0; r < 4; r++)
#pragma unroll
                for (int c = 0; c < 8; c++) acc[r][c] += a[r] * b[c];
        }
        __syncthreads();
    }
#pragma unroll
    for (int r = 0; r < 4; r++) {
        float* row = xe + (size_t)(e0 + ty * 4 + r) * 128;
        float4 o0 = *(const float4*)(row + tx * 4);
        float4 o1 = *(const float4*)(row + 64 + tx * 4);
        o0.x += acc[r][0]; o0.y += acc[r][1]; o0.z += acc[r][2]; o0.w += acc[r][3];
        o1.x += acc[r][4]; o1.y += acc[r][5]; o1.z += acc[r][6]; o1.w += acc[r][7];
        *(float4*)(row + tx * 4) = o0;
        *(float4*)(row + 64 + tx * 4) = o1;
    }
}

// ---------------------------------------------------------------- K6: build z
__global__ void zprep_kernel(const float* __restrict__ x, const float* __restrict__ R,
                             float* __restrict__ z) {
    int idx = blockIdx.x * 256 + threadIdx.x;
    if (idx >= NN * 128) return;
    int n = idx >> 7, c = idx & 127;
    float v0 = x[(size_t)n * 512 + 128 + c];
    float v1 = x[(size_t)n * 512 + 256 + c];
    float v2 = x[(size_t)n * 512 + 384 + c];
    const float* Rn = R + (size_t)n * 9;
    float* zr = z + (size_t)n * 640;
    zr[c] = x[(size_t)n * 512 + c];
    zr[128 + c * 3 + 0] = v0 * Rn[0] + v1 * Rn[3] + v2 * Rn[6];
    zr[128 + c * 3 + 1] = v0 * Rn[1] + v1 * Rn[4] + v2 * Rn[7];
    zr[128 + c * 3 + 2] = v0 * Rn[2] + v1 * Rn[5] + v2 * Rn[8];
    zr[512 + c] = sqrtf(v0 * v0 + v1 * v1 + v2 * v2 + EPSF);
}

// ---------------------------------------------------------------- K7/K8: 64x128-tile GEMM + bias (+gelu)
// grid (ceil(M/64), Nc/128), block 256. Register-prefetch double-buffered stages.
// bias == nullptr -> no bias.
template <int ACT>
__global__ __launch_bounds__(256) void gemm_bias_kernel(const float* __restrict__ A,
                                                        const float* __restrict__ B,
                                                        const float* __restrict__ bias,
                                                        float* __restrict__ C,
                                                        int M, int K, int Nc) {
    __shared__ float As[16][65];
    __shared__ float Bs[16][132];
    int m0 = blockIdx.x * 64;
    int n0_ = blockIdx.y * 128;
    int tid = threadIdx.x;
    int ty = tid >> 4, tx = tid & 15;
    int am = tid >> 2, akq = (tid & 3) * 4;
    int gm = m0 + am;
    int brr = (tid * 2) >> 5, bcc = ((tid * 2) & 31) * 4;
    float acc[4][8];
#pragma unroll
    for (int r = 0; r < 4; r++)
#pragma unroll
        for (int c = 0; c < 8; c++) acc[r][c] = 0.f;
    float4 pa = make_float4(0.f, 0.f, 0.f, 0.f), pb0, pb1;
    if (gm < M) pa = *(const float4*)(A + (size_t)gm * K + akq);
    pb0 = *(const float4*)(B + (size_t)brr * Nc + n0_ + bcc);
    pb1 = *(const float4*)(B + (size_t)brr * Nc + n0_ + bcc + 4);
    for (int kt = 0; kt < K; kt += 16) {
        As[akq + 0][am] = pa.x; As[akq + 1][am] = pa.y;
        As[akq + 2][am] = pa.z; As[akq + 3][am] = pa.w;
        *(float4*)&Bs[brr][bcc] = pb0;
        *(float4*)&Bs[brr][bcc + 4] = pb1;
        __syncthreads();
        if (kt + 16 < K) {
            pa = make_float4(0.f, 0.f, 0.f, 0.f);
            if (gm < M) pa = *(const float4*)(A + (size_t)gm * K + kt + 16 + akq);
            pb0 = *(const float4*)(B + (size_t)(kt + 16 + brr) * Nc + n0_ + bcc);
            pb1 = *(const float4*)(B + (size_t)(kt + 16 + brr) * Nc + n0_ + bcc + 4);
        }
#pragma unroll
        for (int kk = 0; kk < 16; kk++) {
            float a[4], b[8];
#pragma unroll
            for (int r = 0; r < 4; r++) a[r] = As[kk][ty * 4 + r];
            *(float4*)(b + 0) = *(const float4*)&Bs[kk][tx * 4];
            *(float4*)(b + 4) = *(const float4*)&Bs[kk][64 + tx * 4];
#pragma unroll
            for (int r = 0; r < 4; r++)
#pragma unroll
                for (int c = 0; c < 8; c++) acc[r][c] += a[r] * b[c];
        }
        __syncthreads();
    }
#pragma unroll
    for (int r = 0; r < 4; r++) {
        int gm2 = m0 + ty * 4 + r;
        if (gm2 < M) {
#pragma unroll
            for (int c = 0; c < 4; c++) {
                int gc0 = n0_ + tx * 4 + c;
                int gc1 = n0_ + 64 + tx * 4 + c;
                float v = acc[r][c] + (bias ? bias[gc0] : 0.f);
                float w = acc[r][4 + c] + (bias ? bias[gc1] : 0.f);
                if (ACT) {
                    v = 0.5f * v * (1.f + erff(v * 0.70710678118f));
                    w = 0.5f * w * (1.f + erff(w * 0.70710678118f));
                }
                C[(size_t)gm2 * Nc + gc0] = v;
                C[(size_t)gm2 * Nc + gc1] = w;
            }
        }
    }
}

// ---------------------------------------------------------------- K9: finalize local update
__global__ void final_kernel(const float* __restrict__ h, const float* __restrict__ R,
                             float* __restrict__ x) {
    int idx = blockIdx.x * 256 + threadIdx.x;
    if (idx >= NN * 128) return;
    int n = idx >> 7, c = idx & 127;
    const float* hr = h + (size_t)n * 512;
    const float* Rn = R + (size_t)n * 9;
    float h1 = hr[128 + c], h2 = hr[256 + c], h3 = hr[384 + c];
    x[(size_t)n * 512 + c] += hr[c];
    x[(size_t)n * 512 + 128 + c] += Rn[0] * h1 + Rn[1] * h2 + Rn[2] * h3;
    x[(size_t)n * 512 + 256 + c] += Rn[3] * h1 + Rn[4] * h2 + Rn[5] * h3;
    x[(size_t)n * 512 + 384 + c] += Rn[6] * h1 + Rn[7] * h2 + Rn[8] * h3;
}

// ================================================================ launcher
extern "C" void kernel_launch(void* const* d_in, const int* in_sizes, int n_in,
                              void* d_out, int out_size, void* d_ws, size_t ws_size,
                              hipStream_t stream) {
    const float* x_in = (const float*)d_in[0];
    const float* t    = (const float*)d_in[1];
    const float* R    = (const float*)d_in[2];
    const float* xe_in = (const float*)d_in[3];
    const int* ei     = (const int*)d_in[4];
    const float* Wq   = (const float*)d_in[5];
    const float* Wk   = (const float*)d_in[6];
    const float* Wv   = (const float*)d_in[7];
    const float* Wpq  = (const float*)d_in[8];
    const float* Wpk  = (const float*)d_in[9];
    const float* Wpv  = (const float*)d_in[10];
    const float* We   = (const float*)d_in[11];
    const float* gamma = (const float*)d_in[12];
    const float* Wos  = (const float*)d_in[13];
    const float* Wov  = (const float*)d_in[14];
    const float* We1  = (const float*)d_in[15];
    const float* We2  = (const float*)d_in[16];
    const float* luW1 = (const float*)d_in[17];
    const float* lub1 = (const float*)d_in[18];
    const float* luW2 = (const float*)d_in[19];
    const float* lub2 = (const float*)d_in[20];

    float* x  = (float*)d_out;                      // (N,4,128)
    float* xe = (float*)d_out + (size_t)NN * 512;   // (E,128)

    // workspace carve (floats)
    float* fws = (float*)d_ws;
    float* s_old = fws;                     fws += (size_t)NN * 128;
    float* U = fws;                         fws += (size_t)NN * 1792;
    float* logits = fws;                    fws += (size_t)EE * 8;
    int* iws = (int*)fws;
    int* counts = iws;                      iws += NN + 1;
    int* offs = iws;                        iws += NN + 1;
    int* cursor = iws;                      iws += NN + 1;
    int* perm = iws;                        iws += EE;

    // aliased by lifetime inside U
    float* q  = U;
    float* k  = U + (size_t)NN * 128;
    float* vv = U + (size_t)NN * 256;
    float* pq = U + (size_t)NN * 384;
    float* pk = U + (size_t)NN * 576;
    float* pv = U + (size_t)NN * 768;
    float* out_s = U + (size_t)NN * 960;
    float* out_p = U + (size_t)NN * 1088;
    float* Y1 = U + (size_t)NN * 1280;      // node-side We1 projections (dead before h written)
    float* Y2 = U + (size_t)NN * 1408;
    float* z  = U;                          // after attention phase
    float* h1 = U + (size_t)NN * 640;
    float* h  = U + (size_t)NN * 1280;

    const int* srcp = ei;
    const int* dstp = ei + EE;

    hipMemcpyAsync(x, x_in, (size_t)NN * 512 * 4, hipMemcpyDeviceToDevice, stream);
    hipMemcpyAsync(xe, xe_in, (size_t)EE * 128 * 4, hipMemcpyDeviceToDevice, stream);
    hipMemsetAsync(counts, 0, (NN + 1) * 4, stream);
    hipMemsetAsync(cursor, 0, (NN + 1) * 4, stream);
    count_kernel<<<(EE + 255) / 256, 256, 0, stream>>>(dstp, counts);
    scan_kernel<<<1, 1024, 0, stream>>>(counts, offs);
    fill_kernel<<<(EE + 255) / 256, 256, 0, stream>>>(dstp, offs, cursor, perm);

    for (int l = 0; l < LL; l++) {
        const float* Wq_l = Wq + (size_t)l * 256 * 128;
        const float* Wk_l = Wk + (size_t)l * 256 * 128;
        const float* Wv_l = Wv + (size_t)l * 256 * 128;
        const float* Wpq_l = Wpq + (size_t)l * 128 * 64;
        const float* Wpk_l = Wpk + (size_t)l * 128 * 64;
        const float* Wpv_l = Wpv + (size_t)l * 128 * 64;
        const float* We_l = We + (size_t)l * 128 * 8;
        const float* gamma_l = gamma + (size_t)l * 8;
        const float* Wos_l = Wos + (size_t)l * 192 * 128;
        const float* Wov_l = Wov + (size_t)l * 64 * 128;
        const float* We1_l = We1 + (size_t)l * 384 * 128;
        const float* We2_l = We2 + (size_t)l * 128 * 128;
        const float* luW1_l = luW1 + (size_t)l * 640 * 640;
        const float* lub1_l = lub1 + (size_t)l * 640;
        const float* luW2_l = luW2 + (size_t)l * 640 * 512;
        const float* lub2_l = lub2 + (size_t)l * 512;

        proj_kernel<<<(NN + 7) / 8, 256, 0, stream>>>(x, t, Wq_l, Wk_l, Wv_l, Wpq_l, Wpk_l,
                                                      Wpv_l, s_old, q, k, vv, pq, pk, pv);
        // node-side pieces of the edge-MLP first GEMM:
        // Y1 = s_old @ We1[0:128], Y2 = s_old @ We1[128:256]
        gemm_bias_kernel<0><<<dim3((NN + 63) / 64, 1), 256, 0, stream>>>(
            s_old, We1_l, nullptr, Y1, NN, 128, 128);
        gemm_bias_kernel<0><<<dim3((NN + 63) / 64, 1), 256, 0, stream>>>(
            s_old, We1_l + 128 * 128, nullptr, Y2, NN, 128, 128);
        logits_kernel<<<EE / 32, 256, 0, stream>>>(srcp, dstp, q, k, pq, pk, xe, We_l, gamma_l,
                                                   logits);
        agg_kernel<<<NN / 4, 256, 0, stream>>>(offs, perm, srcp, logits, vv, pv, out_s, out_p);
        attn_out_kernel<<<(NN + 7) / 8, 256, 0, stream>>>(out_s, out_p, Wos_l, Wov_l, x);
        edge_mlp_kernel<<<EE / 64, 256, 0, stream>>>(srcp, dstp, Y1, Y2, We1_l + 256 * 128,
                                                     We2_l, xe);
        zprep_kernel<<<(NN * 128 + 255) / 256, 256, 0, stream>>>(x, R, z);
        gemm_bias_kernel<1><<<dim3((NN + 63) / 64, 5), 256, 0, stream>>>(z, luW1_l, lub1_l, h1,
                                                                         NN, 640, 640);
        gemm_bias_kernel<0><<<dim3((NN + 63) / 64, 4), 256, 0, stream>>>(h1, luW2_l, lub2_l, h,
                                                                         NN, 640, 512);
        final_kernel<<<(NN * 128 + 255) / 256, 256, 0, stream>>>(h, R, x);
    }
}